// Round 2
// 580.870 us; speedup vs baseline: 1.2035x; 1.2035x over previous
//
#include <hip/hip_runtime.h>

// Problem: N=32, C=1024, B=1024
//   K = Wk@X[n] + Wk0 ; Q = Wq@X[n] + Wq0
//   Y[q,k] = (Q[:,q].K[:,k]) / sqrt(max(|Q_q|^2 |K_k|^2, 1e-12))
//   SM = softmax over q ; Z = X @ SM  -> [N,C,B] fp32
//
// NT GEMM (both operands k-contiguous bf16), 256x256 tile, BK=64, 8 waves,
// 8-phase counted-vmcnt schedule (T2 swizzle + T3/T4 pipeline + T5 setprio).
// Norms fused into GEMM1 epilogue. Softmax fused into GEMM2/GEMM3:
// |Y|<=1 (cosine) so exp uses fixed shift M=1 (no max pass); the
// normalizer 1/S factors out of Z and is applied in GEMM3's epilogue.
//
// NOTE: __launch_bounds__(512) with NO min-wave clause. (512,2) would cap
// VGPRs at 128 -> acc spills to scratch -> scratch VMEM traffic corrupts
// the hand-counted vmcnt(6) pipeline. ~212 VGPRs needed; 2 waves/SIMD.

typedef __bf16 bf16x8 __attribute__((ext_vector_type(8)));
typedef float  f32x4  __attribute__((ext_vector_type(4)));

#define LOAD16_LDS(g, l)                                                       \
  __builtin_amdgcn_global_load_lds(                                            \
      (const __attribute__((address_space(1))) void*)(g),                      \
      (__attribute__((address_space(3))) void*)(l), 16, 0, 0)

#define FENCE() asm volatile("" ::: "memory")
#define SBAR()                                                                 \
  do { FENCE(); __builtin_amdgcn_s_barrier(); FENCE(); } while (0)
#define LGKM0()                                                                \
  do { asm volatile("s_waitcnt lgkmcnt(0)" ::: "memory");                      \
       __builtin_amdgcn_sched_barrier(0); } while (0)
#define VMW(n)                                                                 \
  do { asm volatile("s_waitcnt vmcnt(" #n ")" ::: "memory");                   \
       __builtin_amdgcn_sched_barrier(0); } while (0)
#define MFMA16(a, b, c) __builtin_amdgcn_mfma_f32_16x16x32_bf16((a), (b), (c), 0, 0, 0)

// ---------------------------------------------------------------- converts
__global__ __launch_bounds__(256) void convert_w(
    const float* __restrict__ Wk, const float* __restrict__ Wq,
    const float* __restrict__ Wk0, const float* __restrict__ Wq0,
    __bf16* __restrict__ Wb, float* __restrict__ bias2) {
  int i = blockIdx.x * 256 + threadIdx.x;              // 0 .. 2M-1
  if (i < 1048576) Wb[i] = (__bf16)Wk[i];
  else             Wb[i] = (__bf16)Wq[i - 1048576];
  if (i < 1024) bias2[i] = Wk0[i];
  if (i >= 1048576 && i < 1048576 + 1024) bias2[1024 + (i - 1048576)] = Wq0[i - 1048576];
}

__global__ __launch_bounds__(256) void convert_x(
    const float* __restrict__ X, __bf16* __restrict__ Xb, __bf16* __restrict__ Xtb) {
  const int n = blockIdx.z;
  const int c0 = blockIdx.y * 32, b0 = blockIdx.x * 32;
  __shared__ float t[32][33];
  const int tx = threadIdx.x, ty = threadIdx.y;        // 32 x 8
  const float* Xn = X + (size_t)n * 1024 * 1024;
  __bf16* Xbn = Xb + (size_t)n * 1024 * 1024;
  __bf16* Xtn = Xtb + (size_t)n * 1024 * 1024;
#pragma unroll
  for (int i = 0; i < 4; ++i) {
    int c = c0 + ty + i * 8;
    float v = Xn[(size_t)c * 1024 + b0 + tx];
    Xbn[(size_t)c * 1024 + b0 + tx] = (__bf16)v;
    t[ty + i * 8][tx] = v;
  }
  __syncthreads();
#pragma unroll
  for (int i = 0; i < 4; ++i) {
    int b = b0 + ty + i * 8;
    Xtn[(size_t)b * 1024 + c0 + tx] = (__bf16)t[tx][ty + i * 8];
  }
}

// ---------------------------------------------------------------- NT GEMM
// C[m,n'] = sum_k A[m,k] * B[n',k]; A:[M][lda], B:[N][ldb], bf16 rows k-contig.
// 256x256 tile, BK=64, 8 waves (2Mx4N), per-wave C = 128x64.
// LDS per buffer: A[256][64] bf16 (32KB) + B[256][64] (32KB); 2 buffers.
// LDS element (row, colbytes cb) stored at row*128 + (cb ^ ((row&7)<<4));
// staging keeps LDS dest linear and pre-swizzles the GLOBAL source column.
// Chunk c (8KB) of an operand covers rows c*64..c*64+63; thread t supplies
// row c*64 + (t>>3), global col element 8*((t&7)^((t>>3)&7)).
//
// Pipeline (per K-tile, 4 phases; 2 loads = 1 "unit" issued per phase):
//   tile T units: u0=B01, u1=B23, u2=A0A2, u3=A1A3
//   T.p0: read B(all)+A(mi0,1); issue u3(T+1)->nxt
//   T.p1: read A(mi2,3);        issue u0(T+2)->cur.B   (B retired at p0)
//   T.p2: read A(mi4,5);        issue u1(T+2)->cur.B
//   T.p3: read A(mi6,7);        issue u2(T+2)->cur.A02 (retired at p1);
//         vmcnt(6) [last 2 boundaries: vmcnt(0)]
//   each phase: barrier; lgkmcnt(0); setprio(1); 16 MFMA; setprio(0); barrier
//
// EPI 0: bf16 out + bias[col]; fused per-row sum-of-squares -> atomicAdd
// EPI 1: e = exp(v*rsqrt(max(rowS*colS,eps)) - 1) bf16 out; row-sum -> sq0
// EPI 2: f32 out * (1/colS[col])                   (Z, softmax normalizer)
template <int EPI>
__global__ __launch_bounds__(512) void gemm256(
    const __bf16* __restrict__ A, const __bf16* __restrict__ Bm,
    void* __restrict__ Out, int lda, int ldb, int ldo, int K,
    long long sA, long long sB, long long sO,
    const float* __restrict__ rowS, const float* __restrict__ colS,
    const float* __restrict__ bias,
    float* __restrict__ sq0, float* __restrict__ sq1) {
  extern __shared__ char smem[];
  const int n = blockIdx.z;
  A += (size_t)n * sA;
  Bm += (size_t)n * sB;
  const int tileM = blockIdx.y * 256, tileN = blockIdx.x * 256;

  const int tid = threadIdx.x;                 // 0..511
  const int w = tid >> 6, lane = tid & 63;
  const int wm = w >> 2, wn = w & 3;           // 2 x 4 wave grid
  const int r16 = lane & 15, q16 = lane >> 4;
  const int wb = w * 1024;                     // wave slice inside an 8KB chunk

  // ---- staging source addresses (pre-swizzled global column)
  const int srow = tid >> 3;                                 // 0..63
  const int scol8 = ((tid & 7) ^ (srow & 7)) * 8;            // element offset
  const __bf16* gA[4];
  const __bf16* gB[4];
#pragma unroll
  for (int c = 0; c < 4; ++c) {
    gA[c] = A + (size_t)(tileM + c * 64 + srow) * lda + scol8;
    gB[c] = Bm + (size_t)(tileN + c * 64 + srow) * ldb + scol8;
  }

  // ---- fragment-read addressing
  const int sw = (r16 & 7) << 4;
  const int cc0 = (q16 * 16) ^ sw;             // k-half 0, bytes within row
  const int cc1 = cc0 ^ 64;                    // k-half 1
  const int aRow = (wm * 128 + r16) * 128;     // + mi*2048
  const int bRow = (wn * 64 + r16) * 128;      // + ni*2048

  f32x4 acc[8][4];
#pragma unroll
  for (int i = 0; i < 8; ++i)
#pragma unroll
    for (int j = 0; j < 4; ++j) acc[i][j] = (f32x4){0.f, 0.f, 0.f, 0.f};

  const int NT = K >> 6;                       // 16 K-tiles

  // ---- prologue: tile0 u0..u3 (koff 0) + tile1 u0..u2 (koff 64)
  {
    char* A0 = smem;
    char* B0 = smem + 32768;
    char* A1 = smem + 65536;
    char* B1 = smem + 65536 + 32768;
    LOAD16_LDS(gB[0], B0 + 0 * 8192 + wb);
    LOAD16_LDS(gB[1], B0 + 1 * 8192 + wb);
    FENCE();
    LOAD16_LDS(gB[2], B0 + 2 * 8192 + wb);
    LOAD16_LDS(gB[3], B0 + 3 * 8192 + wb);
    FENCE();
    LOAD16_LDS(gA[0], A0 + 0 * 8192 + wb);
    LOAD16_LDS(gA[2], A0 + 2 * 8192 + wb);
    FENCE();
    LOAD16_LDS(gA[1], A0 + 1 * 8192 + wb);
    LOAD16_LDS(gA[3], A0 + 3 * 8192 + wb);
    FENCE();
    LOAD16_LDS(gB[0] + 64, B1 + 0 * 8192 + wb);
    LOAD16_LDS(gB[1] + 64, B1 + 1 * 8192 + wb);
    FENCE();
    LOAD16_LDS(gB[2] + 64, B1 + 2 * 8192 + wb);
    LOAD16_LDS(gB[3] + 64, B1 + 3 * 8192 + wb);
    FENCE();
    LOAD16_LDS(gA[0] + 64, A1 + 0 * 8192 + wb);
    LOAD16_LDS(gA[2] + 64, A1 + 2 * 8192 + wb);
    VMW(6);                                    // tile0 fully resident
    SBAR();
  }

  int kU3 = 64, kU0 = 128, kU1 = 128, kU2 = 128;

  for (int t = 0; t < NT; ++t) {
    char* Ab = smem + (size_t)((t & 1) * 65536);
    char* Bb = Ab + 32768;
    char* An = smem + (size_t)(((t & 1) ^ 1) * 65536);

    // B fragments for the whole tile (read once, held in regs)
    bf16x8 bfr[4][2];
#pragma unroll
    for (int ni = 0; ni < 4; ++ni) {
      bfr[ni][0] = *(const bf16x8*)(Bb + bRow + ni * 2048 + cc0);
      bfr[ni][1] = *(const bf16x8*)(Bb + bRow + ni * 2048 + cc1);
    }

#pragma unroll
    for (int p = 0; p < 4; ++p) {
      bf16x8 af[2][2];
#pragma unroll
      for (int j = 0; j < 2; ++j) {
        af[j][0] = *(const bf16x8*)(Ab + aRow + (2 * p + j) * 2048 + cc0);
        af[j][1] = *(const bf16x8*)(Ab + aRow + (2 * p + j) * 2048 + cc1);
      }
      if (p == 0) {
        if (kU3 < K) {
          LOAD16_LDS(gA[1] + kU3, An + 1 * 8192 + wb);
          LOAD16_LDS(gA[3] + kU3, An + 3 * 8192 + wb);
          kU3 += 64;
        }
      } else if (p == 1) {
        if (kU0 < K) {
          LOAD16_LDS(gB[0] + kU0, Bb + 0 * 8192 + wb);
          LOAD16_LDS(gB[1] + kU0, Bb + 1 * 8192 + wb);
          kU0 += 64;
        }
      } else if (p == 2) {
        if (kU1 < K) {
          LOAD16_LDS(gB[2] + kU1, Bb + 2 * 8192 + wb);
          LOAD16_LDS(gB[3] + kU1, Bb + 3 * 8192 + wb);
          kU1 += 64;
        }
      } else {
        if (kU2 < K) {
          LOAD16_LDS(gA[0] + kU2, Ab + 0 * 8192 + wb);
          LOAD16_LDS(gA[2] + kU2, Ab + 2 * 8192 + wb);
          kU2 += 64;
        }
        if (t < NT - 2) { VMW(6); } else { VMW(0); }  // next tile resident
      }
      SBAR();
      LGKM0();
      __builtin_amdgcn_s_setprio(1);
#pragma unroll
      for (int ni = 0; ni < 4; ++ni) {
#pragma unroll
        for (int j = 0; j < 2; ++j) {
          acc[2 * p + j][ni] = MFMA16(af[j][0], bfr[ni][0], acc[2 * p + j][ni]);
          acc[2 * p + j][ni] = MFMA16(af[j][1], bfr[ni][1], acc[2 * p + j][ni]);
        }
      }
      __builtin_amdgcn_s_setprio(0);
      SBAR();
    }
  }

  // ---------------------------------------------------------------- epilogue
  const int rowBase = tileM + wm * 128;
  const int colBase = tileN + wn * 64;
  if (EPI == 0) {
    // bf16 store (+bias) and per-row sum of squares of the ROUNDED values.
    float* sqp = (tileN < 1024) ? sq0 : sq1;
    float bs[4];
#pragma unroll
    for (int ni = 0; ni < 4; ++ni) bs[ni] = bias[colBase + ni * 16 + r16];
#pragma unroll
    for (int mi = 0; mi < 8; ++mi) {
#pragma unroll
      for (int t_ = 0; t_ < 4; ++t_) {
        const int grow = rowBase + mi * 16 + q16 * 4 + t_;
        float ss = 0.f;
#pragma unroll
        for (int ni = 0; ni < 4; ++ni) {
          const int gcol = colBase + ni * 16 + r16;
          const __bf16 bv = (__bf16)(acc[mi][ni][t_] + bs[ni]);
          ((__bf16*)Out)[(size_t)n * sO + (size_t)grow * ldo + gcol] = bv;
          const float f = (float)bv;
          ss += f * f;
        }
        ss += __shfl_xor(ss, 1);
        ss += __shfl_xor(ss, 2);
        ss += __shfl_xor(ss, 4);
        ss += __shfl_xor(ss, 8);
        if (r16 == 0) atomicAdd(&sqp[n * 1024 + grow], ss);
      }
    }
  } else if (EPI == 1) {
    // e = exp(y - 1), y = cosine in [-1,1] -> no max pass needed.
    float cs[4];
#pragma unroll
    for (int ni = 0; ni < 4; ++ni)
      cs[ni] = colS[n * 1024 + colBase + ni * 16 + r16];
#pragma unroll
    for (int mi = 0; mi < 8; ++mi) {
#pragma unroll
      for (int t_ = 0; t_ < 4; ++t_) {
        const int grow = rowBase + mi * 16 + q16 * 4 + t_;
        const float rs = rowS[n * 1024 + grow];
        float ss = 0.f;
#pragma unroll
        for (int ni = 0; ni < 4; ++ni) {
          const int gcol = colBase + ni * 16 + r16;
          const float y = acc[mi][ni][t_] * rsqrtf(fmaxf(rs * cs[ni], 1e-12f));
          const __bf16 e = (__bf16)__expf(y - 1.0f);
          ((__bf16*)Out)[(size_t)n * sO + (size_t)grow * ldo + gcol] = e;
          ss += (float)e;
        }
        ss += __shfl_xor(ss, 1);
        ss += __shfl_xor(ss, 2);
        ss += __shfl_xor(ss, 4);
        ss += __shfl_xor(ss, 8);
        if (r16 == 0) atomicAdd(&sq0[n * 1024 + grow], ss);
      }
    }
  } else {
    float inv[4];
#pragma unroll
    for (int ni = 0; ni < 4; ++ni)
      inv[ni] = 1.0f / colS[n * 1024 + colBase + ni * 16 + r16];
#pragma unroll
    for (int mi = 0; mi < 8; ++mi)
#pragma unroll
      for (int ni = 0; ni < 4; ++ni)
#pragma unroll
        for (int t_ = 0; t_ < 4; ++t_) {
          const int grow = rowBase + mi * 16 + q16 * 4 + t_;
          const int gcol = colBase + ni * 16 + r16;
          ((float*)Out)[(size_t)n * sO + (size_t)grow * ldo + gcol] =
              acc[mi][ni][t_] * inv[ni];
        }
  }
}

// ---------------------------------------------------------------- launch
extern "C" void kernel_launch(void* const* d_in, const int* in_sizes, int n_in,
                              void* d_out, int out_size, void* d_ws, size_t ws_size,
                              hipStream_t stream) {
  const float* X   = (const float*)d_in[0];
  const float* Wk  = (const float*)d_in[1];
  const float* Wq  = (const float*)d_in[2];
  const float* Wk0 = (const float*)d_in[3];
  const float* Wq0 = (const float*)d_in[4];

  char* ws = (char*)d_ws;
  const size_t MB = 1ull << 20;
  // layout (peak ~261 MB): ET aliases Xtb (dead after GEMM1)
  __bf16* Xb   = (__bf16*)(ws);              //  64 MB  [N][C][B]
  __bf16* Xtb  = (__bf16*)(ws + 64 * MB);    //  64 MB  [N][B][C]
  __bf16* ET   = (__bf16*)(ws + 64 * MB);    //  64 MB  alias   [N][Bk][Bq]
  __bf16* Wb   = (__bf16*)(ws + 128 * MB);   //   4 MB  [2C][C]
  __bf16* KQT  = (__bf16*)(ws + 132 * MB);   // 128 MB  [N][B][2C]  (K^T | Q^T)
  float*  DK2  = (float*)(ws + 260 * MB);            // 128 KB
  float*  DQ2  = (float*)(ws + 260 * MB + 128 * 1024);
  float*  S    = (float*)(ws + 260 * MB + 256 * 1024); // ET row sums
  float*  bias2= (float*)(ws + 260 * MB + 384 * 1024);

  const long long M1 = 1024LL * 1024LL;

  // Opt-in for 128 KiB dynamic LDS. Unconditional: cheap host-side calls,
  // and a one-shot static guard could be defeated by graph capture timing.
  hipFuncSetAttribute(reinterpret_cast<const void*>(&gemm256<0>),
                      hipFuncAttributeMaxDynamicSharedMemorySize, 131072);
  hipFuncSetAttribute(reinterpret_cast<const void*>(&gemm256<1>),
                      hipFuncAttributeMaxDynamicSharedMemorySize, 131072);
  hipFuncSetAttribute(reinterpret_cast<const void*>(&gemm256<2>),
                      hipFuncAttributeMaxDynamicSharedMemorySize, 131072);

  hipMemsetAsync(DK2, 0, 3 * 128 * 1024, stream);  // zero DK2, DQ2, S

  convert_w<<<8192, 256, 0, stream>>>(Wk, Wq, Wk0, Wq0, Wb, bias2);
  convert_x<<<dim3(32, 32, 32), dim3(32, 8), 0, stream>>>(X, Xb, Xtb);

  // GEMM1: KQT[n][b][c2] = sum_d Xtb[n][b][d] * Wb[c2][d] + bias2[c2]
  //        fused: DK2[n][b] = sum K^2, DQ2[n][b] = sum Q^2
  gemm256<0><<<dim3(8, 4, 32), 512, 131072, stream>>>(
      Xtb, Wb, KQT, 1024, 1024, 2048, 1024, M1, 0LL, 2 * M1,
      nullptr, nullptr, bias2, DK2, DQ2);

  // GEMM2: ET[n][k][q] = exp(cos(K_k,Q_q) - 1)  (bf16), S[n][k] = row sums
  gemm256<1><<<dim3(4, 4, 32), 512, 131072, stream>>>(
      KQT, KQT + 1024, ET, 2048, 2048, 1024, 1024, 2 * M1, 2 * M1, M1,
      DK2, DQ2, nullptr, S, nullptr);

  // GEMM3: Z[n][c][j] = (sum_q Xb[n][c][q] * ET[n][j][q]) / S[n][j]
  gemm256<2><<<dim3(4, 4, 32), 512, 131072, stream>>>(
      Xb, ET, (float*)d_out, 1024, 1024, 1024, 1024, M1, M1, M1,
      nullptr, S, nullptr, nullptr, nullptr);
}